// Round 1
// baseline (1393.875 us; speedup 1.0000x reference)
//
#include <hip/hip_runtime.h>

// SSFM on MI355X. N = 262144 = 512*512, B = 4 batches.
// Four-step FFT; spectrum kept in digit-permuted order (disp table permuted to match).
// Per SSFM step: kernel A (rows) + kernel B (cols). 131 kernels + setup.

static constexpr double PI_D = 3.14159265358979323846;

__device__ __forceinline__ float2 cadd(float2 a, float2 b){ return make_float2(a.x+b.x, a.y+b.y); }
__device__ __forceinline__ float2 csub(float2 a, float2 b){ return make_float2(a.x-b.x, a.y-b.y); }
__device__ __forceinline__ float2 cmul(float2 a, float2 b){
  return make_float2(fmaf(a.x, b.x, -(a.y*b.y)), fmaf(a.x, b.y, a.y*b.x));
}

// Bank-decorrelating bijection on [0,512): XOR high base-8 digits into lower ones.
// Makes every exchange / tile access pattern spread evenly (<=4-way on b64).
__device__ __forceinline__ int sg(int e){
  int d2 = (e>>6)&7, d1 = (e>>3)&7;
  return e ^ (d2<<3) ^ d1 ^ d2;
}

// 8-point DFT. INV=0: w8 = e^{-2pi i/8} (forward); INV=1: conjugate (inverse, unscaled).
template<int INV>
__device__ __forceinline__ void dft8(float2 r[8]){
  const float RS = 0.7071067811865476f;
  float2 t0=cadd(r[0],r[4]), t4=csub(r[0],r[4]);
  float2 t1=cadd(r[1],r[5]), t5=csub(r[1],r[5]);
  float2 t2=cadd(r[2],r[6]), t6=csub(r[2],r[6]);
  float2 t3=cadd(r[3],r[7]), t7=csub(r[3],r[7]);
  float2 u1,u2,u3;
  if(!INV){
    u1 = make_float2((t5.x+t5.y)*RS, (t5.y-t5.x)*RS);   // *(1-i)/sqrt2
    u2 = make_float2(t6.y, -t6.x);                      // *(-i)
    u3 = make_float2((t7.y-t7.x)*RS, -(t7.x+t7.y)*RS);  // *(-1-i)/sqrt2
  } else {
    u1 = make_float2((t5.x-t5.y)*RS, (t5.x+t5.y)*RS);   // *(1+i)/sqrt2
    u2 = make_float2(-t6.y, t6.x);                      // *(+i)
    u3 = make_float2(-(t7.x+t7.y)*RS, (t7.x-t7.y)*RS);  // *(-1+i)/sqrt2
  }
  float2 e0=cadd(t0,t2), e1=csub(t0,t2), e2=cadd(t1,t3), e3=csub(t1,t3);
  float2 f3 = (!INV)? make_float2(e3.y,-e3.x) : make_float2(-e3.y,e3.x);
  r[0]=cadd(e0,e2); r[4]=csub(e0,e2); r[2]=cadd(e1,f3); r[6]=csub(e1,f3);
  float2 o0=cadd(t4,u2), o1=csub(t4,u2), o2=cadd(u1,u3), o3=csub(u1,u3);
  float2 g3 = (!INV)? make_float2(o3.y,-o3.x) : make_float2(-o3.y,o3.x);
  r[1]=cadd(o0,o2); r[5]=csub(o0,o2); r[3]=cadd(o1,g3); r[7]=csub(o1,g3);
}

// 512-point FFT per wave. Forward (INV=0): input r[m] = x[l+64m] natural;
// output reg q <-> X[64q + 8*(l&7) + (l>>3)] (digit order).
// Inverse (INV=1): input in that digit order; output r[m] = x[l+64m], UNSCALED (x512).
// ex: per-wave 512-slot LDS region (addressed through sg()). Intra-wave LDS is in-order.
template<int INV>
__device__ __forceinline__ void fft512(float2 r[8], int l, float2* ex){
  const float W512 = (float)(2.0*PI_D/512.0);
  const float W64  = (float)(2.0*PI_D/64.0);
  int j = l>>3, p = l&7;
  float s,c;
  if(!INV){
    dft8<0>(r);
    __sincosf(-W512*(float)l, &s, &c);
    float2 w = make_float2(c,s), cur = w;
    #pragma unroll
    for(int q=1;q<8;q++){ r[q]=cmul(r[q],cur); cur=cmul(cur,w); }
    #pragma unroll
    for(int q=0;q<8;q++) ex[sg(l + 64*q)] = r[q];
    #pragma unroll
    for(int m=0;m<8;m++) r[m] = ex[sg(64*j + p + 8*m)];
    dft8<0>(r);
    __sincosf(-W64*(float)p, &s, &c);
    w = make_float2(c,s); cur = w;
    #pragma unroll
    for(int q=1;q<8;q++){ r[q]=cmul(r[q],cur); cur=cmul(cur,w); }
    #pragma unroll
    for(int q=0;q<8;q++) ex[sg(64*j + p + 8*q)] = r[q];
    #pragma unroll
    for(int m=0;m<8;m++) r[m] = ex[sg(64*j + 8*p + m)];
    dft8<0>(r);
  } else {
    dft8<1>(r);                                   // over q1 -> t2[64j+8p+m]
    #pragma unroll
    for(int m=0;m<8;m++) ex[sg(64*j + 8*p + m)] = r[m];
    #pragma unroll
    for(int q=0;q<8;q++) r[q] = ex[sg(64*j + p + 8*q)];
    __sincosf(W64*(float)p, &s, &c);
    float2 w = make_float2(c,s), cur = w;
    #pragma unroll
    for(int q=1;q<8;q++){ r[q]=cmul(r[q],cur); cur=cmul(cur,w); }
    dft8<1>(r);                                   // -> t1[64j+p+8m]
    #pragma unroll
    for(int m=0;m<8;m++) ex[sg(64*j + p + 8*m)] = r[m];
    #pragma unroll
    for(int q=0;q<8;q++) r[q] = ex[sg(l + 64*q)];
    __sincosf(W512*(float)l, &s, &c);
    w = make_float2(c,s); cur = w;
    #pragma unroll
    for(int q=1;q<8;q++){ r[q]=cmul(r[q],cur); cur=cmul(cur,w); }
    dft8<1>(r);                                   // -> x[l+64m]
  }
}

// Precompute permuted dispersion tables (dz and dz/2), with attenuation and 1/N folded in.
// Phase replicates the reference's fp32 op order exactly (coherent over 65 steps),
// then double sincos of that phase.
__global__ __launch_bounds__(512) void kSetup(float2* __restrict__ dispF, float2* __restrict__ dispH){
  int m  = blockIdx.x*512 + threadIdx.x;       // storage index = k1*512 + k2
  int k1 = m >> 9, k2 = m & 511;
  int k  = k1 + (k2 << 9);                     // true frequency bin
  int ks = (k < 131072) ? k : k - 262144;
  float fv  = (float)ks / 262144.0f;           // exact (matches ref f after fftshift)
  float tpf = 6.28318548202514648f * fv;       // 2*float32(pi)*f
  float e2  = tpf * tpf;
  const float bh = 10.8350000381469727f;       // -(float32(-21.67)/2)
  float phF = (bh * 1.25f)  * e2;              // full-dz phase, fp32 like reference
  float phH = (bh * 0.625f) * e2;              // half-dz
  double sF,cF,sH,cH;
  sincos((double)phF, &sF, &cF);
  sincos((double)phH, &sH, &cH);
  const float aco = -0.023000000044703484f;    // float32(-ALPHA/2)
  double scF = exp((double)(aco*1.25f))  / 262144.0;
  double scH = exp((double)(aco*0.625f)) / 262144.0;
  dispF[m] = make_float2((float)(cF*scF), (float)(sF*scF));
  dispH[m] = make_float2((float)(cH*scH), (float)(sH*scH));
}

// Kernel A: rows (contiguous). row k1: forward row-FFT -> *dispPerm -> inverse row-FFT
// -> *exp(+2pi i k1 n2 / N). 8 waves = 8 rows per block; per-wave private LDS exchange.
__global__ __launch_bounds__(512) void kA(const float2* __restrict__ src, float2* __restrict__ dst,
                                          const float2* __restrict__ disp){
  __shared__ float2 ex[8][512];
  int t = threadIdx.x, w = t>>6, l = t&63;
  int k1 = blockIdx.x*8 + w;
  size_t base = ((size_t)blockIdx.y<<18) + (size_t)k1*512;
  const float2* s = src + base;
  float2* d = dst + base;
  float2 r[8];
  #pragma unroll
  for(int m=0;m<8;m++) r[m] = s[l + 64*m];
  fft512<0>(r, l, ex[w]);
  int p=l&7, j=l>>3;
  const float2* dp = disp + (size_t)k1*512;
  #pragma unroll
  for(int q=0;q<8;q++) r[q] = cmul(r[q], dp[64*q + 8*p + j]);
  fft512<1>(r, l, ex[w]);
  // inverse four-step twiddle e^{+2pi i k1 n2 / N}, n2 = l + 64m (incremental chain)
  float c1 = (float)(2.0*PI_D/262144.0)*(float)k1;
  float sb,cb,ss,cs;
  __sincosf(c1*(float)l, &sb, &cb);
  __sincosf(c1*64.0f,    &ss, &cs);
  float2 tw = make_float2(cb,sb), st = make_float2(cs,ss);
  #pragma unroll
  for(int m=0;m<8;m++){ d[l+64*m] = cmul(r[m], tw); tw = cmul(tw, st); }
}

// Kernel B: columns, staged through a 512x8 LDS tile for coalescing.
// MODE 0: init  (load input, forward col-FFT, twiddle, store)
// MODE 1: mid   (inverse col-FFT -> window -> Kerr phase -> forward col-FFT -> twiddle)
// MODE 2: final (inverse col-FFT -> write real/imag planes of output)
template<int MODE>
__global__ __launch_bounds__(512) void kB(const float* __restrict__ xr, const float* __restrict__ xi,
                                          const float2* __restrict__ src, float2* __restrict__ dst,
                                          float* __restrict__ outp){
  __shared__ float2 tile[8][514];              // +2 pad per column slice (bank spread)
  int t=threadIdx.x, w=t>>6, l=t&63;
  int c0 = blockIdx.x*8;
  size_t base = ((size_t)blockIdx.y<<18);
  // cooperative coalesced tile load (rows = n1 or k1; cols = n2)
  #pragma unroll
  for(int i=0;i<8;i++){
    int rr = i*64 + (t>>3), cc = t&7;
    size_t a = base + (size_t)rr*512 + (size_t)(c0 + cc);
    if(MODE==0) tile[cc][sg(rr)] = make_float2(xr[a], xi[a]);
    else        tile[cc][sg(rr)] = src[a];
  }
  __syncthreads();
  float2 r[8];
  int p=l&7, j=l>>3;
  int n2 = c0 + w;
  if(MODE==0){
    #pragma unroll
    for(int m=0;m<8;m++) r[m] = tile[w][sg(l + 64*m)];     // natural n1 order
  } else {
    #pragma unroll
    for(int q=0;q<8;q++) r[q] = tile[w][sg(64*q + 8*p + j)]; // digit order (k1)
    fft512<1>(r, l, tile[w]);                               // -> time domain x[n1=l+64m]
  }
  if(MODE==1){
    #pragma unroll
    for(int m=0;m<8;m++){
      int n1 = l + 64*m;
      float wv = 1.0f;
      if(n1==0 && n2<100){
        float ang = (6.28318548202514648f*(float)n2)*0.005f;         // 2pi k/200
        wv = 0.54f - 0.46f*cosf(ang);
      } else if(n1==511 && n2>=412){
        float ang = (6.28318548202514648f*(float)(n2-312))*0.005f;
        wv = 0.54f - 0.46f*cosf(ang);
      }
      float2 qv = make_float2(r[m].x*wv, r[m].y*wv);
      float aq2 = fmaf(qv.x,qv.x, qv.y*qv.y);
      float phi = (aq2 * 1.26999998092651367f) * (-1.25f);           // gamma*(-dz), fp32 order
      float sp,cp; __sincosf(phi,&sp,&cp);
      r[m] = cmul(qv, make_float2(cp,sp));
    }
  }
  if(MODE==2){
    #pragma unroll
    for(int m=0;m<8;m++) tile[w][sg(l + 64*m)] = r[m];
    __syncthreads();
    #pragma unroll
    for(int i=0;i<8;i++){
      int rr = i*64 + (t>>3), cc = t&7;
      float2 v = tile[cc][sg(rr)];
      size_t a = base + (size_t)rr*512 + (size_t)(c0 + cc);
      outp[a] = v.x;                               // real plane
      outp[(size_t)(1<<20) + a] = v.y;             // imag plane (stride 4*262144)
    }
    return;
  }
  fft512<0>(r, l, tile[w]);                        // start next linear op
  // forward four-step twiddle e^{-2pi i n2 k1 / N}, k1 = 64q + 8p + j
  float c1 = -(float)(2.0*PI_D/262144.0)*(float)n2;
  float sb,cb,ss,cs;
  __sincosf(c1*(float)(8*p + j), &sb, &cb);
  __sincosf(c1*64.0f,            &ss, &cs);
  float2 tw=make_float2(cb,sb), st=make_float2(cs,ss);
  #pragma unroll
  for(int q=0;q<8;q++){ r[q]=cmul(r[q],tw); tw=cmul(tw,st); }
  #pragma unroll
  for(int q=0;q<8;q++) tile[w][sg(64*q + 8*p + j)] = r[q];
  __syncthreads();
  #pragma unroll
  for(int i=0;i<8;i++){
    int rr = i*64 + (t>>3), cc = t&7;
    dst[base + (size_t)rr*512 + (size_t)(c0 + cc)] = tile[cc][sg(rr)];
  }
}

extern "C" void kernel_launch(void* const* d_in, const int* in_sizes, int n_in,
                              void* d_out, int out_size, void* d_ws, size_t ws_size,
                              hipStream_t stream) {
  (void)in_sizes; (void)n_in; (void)out_size; (void)ws_size;
  const float* xr = (const float*)d_in[0];
  const float* xi = (const float*)d_in[1];
  float* out = (float*)d_out;
  char* ws = (char*)d_ws;
  float2* buf1  = (float2*)ws;                    // 8 MB
  float2* buf2  = (float2*)(ws + ((size_t)8<<20)); // 8 MB
  float2* dispF = (float2*)(ws + ((size_t)16<<20));// 2 MB
  float2* dispH = (float2*)(ws + ((size_t)18<<20));// 2 MB

  dim3 blk(512), g(64,4);
  kSetup<<<dim3(512), blk, 0, stream>>>(dispF, dispH);

  // chain: D(h) [W N D(f)]^63 W N D(h)
  kB<0><<<g, blk, 0, stream>>>(xr, xi, nullptr, buf1, nullptr);
  kA<<<g, blk, 0, stream>>>(buf1, buf2, dispH);
  for(int i=0;i<63;i++){
    kB<1><<<g, blk, 0, stream>>>(nullptr, nullptr, buf2, buf1, nullptr);
    kA<<<g, blk, 0, stream>>>(buf1, buf2, dispF);
  }
  kB<1><<<g, blk, 0, stream>>>(nullptr, nullptr, buf2, buf1, nullptr);
  kA<<<g, blk, 0, stream>>>(buf1, buf2, dispH);
  kB<2><<<g, blk, 0, stream>>>(nullptr, nullptr, buf2, nullptr, out);
}